// Round 4
// baseline (114.052 us; speedup 1.0000x reference)
//
#include <hip/hip_runtime.h>
#include <hip/hip_bf16.h>

typedef __attribute__((ext_vector_type(8))) short short8;
typedef __attribute__((ext_vector_type(4))) short short4v;
typedef __attribute__((ext_vector_type(2))) short short2v;
typedef __attribute__((ext_vector_type(4))) float f32x4;

namespace {
constexpr int NSEQ = 2048;
constexpr int NHEAD = 16;
constexpr int NDIM = 128;
constexpr int BKV = 32;
constexpr int VTS = 40;              // vt_lds row stride (shorts)
constexpr int ROWI = NHEAD * NDIM;   // 2048 ints per seq row
}

// int in [-128,127] -> bf16 bits, exact
__device__ __forceinline__ short i2bf(int v) {
    union { float f; unsigned u; } x; x.f = (float)v;
    return (short)(x.u >> 16);
}
// float -> bf16 bits, RNE
__device__ __forceinline__ short f2bf(float f) {
    union { float f; unsigned u; } x; x.f = f;
    unsigned u = (x.u + 0x7fffu + ((x.u >> 16) & 1u)) >> 16;
    return (short)u;
}

__global__ __launch_bounds__(512, 4)
void qattn_fwd(const int* __restrict__ qq, const int* __restrict__ kq,
               const int* __restrict__ vq, const float* __restrict__ qsc,
               const float* __restrict__ ksc, const float* __restrict__ vsc,
               float* __restrict__ out)
{
    // 512 blocks: bh fastest (L2 locality), then h2, then jj
    const int id = blockIdx.x;
    const int bh = id & 31;
    const int rest = id >> 5;          // 0..15
    const int jj = rest >> 1;          // pair index 0..7
    const int h2 = rest & 1;           // which 64-row half of the 128-row tile
    const int b = bh >> 4, h = bh & 15;
    const int t = threadIdx.x;
    const int lane = t & 63;
    const int w = t >> 6;              // wave 0..7
    const int g = lane >> 4;           // 0..3
    const int fr = lane & 15;

    __shared__ __align__(16) short k_lds[2][BKV * NDIM];     // 16 KB
    __shared__ __align__(16) short vt_lds[2][NDIM * VTS];    // 20 KB, V^T [d][kv]
    __shared__ __align__(16) short pq[8][4 * 16 * 8];        // 8 KB, P^T per wave

    const float sc2 = qsc[h] * ksc[h] * (0.08838834764831845f * 1.4426950408889634f);
    const float vscale = vsc[h];

    const int jq = (w < 4) ? (15 - jj) : jj;
    const int q0 = jq * 128 + h2 * 64 + (w & 3) * 16;  // this wave's 16 q rows
    const int q_hi = q0 + 15;
    const int nt = (15 - jj) * 4 + h2 * 2 + 2;         // kv tiles staged (heavy coverage)

    const int* kB = kq + (size_t)b * NSEQ * ROWI + h * NDIM;
    const int* vB = vq + (size_t)b * NSEQ * ROWI + h * NDIM;
    const int* qBp = qq + (size_t)b * NSEQ * ROWI + h * NDIM;

    // ---- Q fragments (exact int->bf16), rows q0 + fr ----
    short8 qf[4];
    {
        const int* qp = qBp + (q0 + fr) * ROWI;
        #pragma unroll
        for (int c = 0; c < 4; ++c) {
            const int d = c * 32 + g * 8;
            int4 a0 = *(const int4*)(qp + d);
            int4 a1 = *(const int4*)(qp + d + 4);
            short8 f;
            f[0]=i2bf(a0.x); f[1]=i2bf(a0.y); f[2]=i2bf(a0.z); f[3]=i2bf(a0.w);
            f[4]=i2bf(a1.x); f[5]=i2bf(a1.y); f[6]=i2bf(a1.z); f[7]=i2bf(a1.w);
            qf[c] = f;
        }
    }

    const f32x4 fzero = {0.f, 0.f, 0.f, 0.f};
    f32x4 o_acc[8];                    // O^T: o_acc[dt][r] = O[d=dt*16+g*4+r][q=q0+fr]
    float m_run = -1e30f, l_run = 0.f; // per-lane scalars (lane owns q row q0+fr)
    #pragma unroll
    for (int dt = 0; dt < 8; ++dt) o_acc[dt] = fzero;

    // ---- staging decomposition (512 threads; K 8 ints/thr, V 8 ints/thr) ----
    const int krow = t >> 4;           // 0..31
    const int dk   = (t & 15) * 8;     // 0..120
    const int kv2  = t & 15;           // V: rows 2*kv2, 2*kv2+1
    const int dgv  = t >> 4;           // V: d cols 4*dgv..+3

    int4 ka0, ka1, va0, va1;

    auto ISSUE = [&](int tt) {
        const int kv = tt * BKV;
        const int* kp = kB + (kv + krow) * ROWI + dk;
        ka0 = *(const int4*)kp;
        ka1 = *(const int4*)(kp + 4);
        const int* vp = vB + (kv + 2 * kv2) * ROWI + dgv * 4;
        va0 = *(const int4*)vp;
        va1 = *(const int4*)(vp + ROWI);
    };
    auto WRITE = [&](int tt) {
        const int buf = tt & 1;
        short8 kk;
        kk[0]=i2bf(ka0.x); kk[1]=i2bf(ka0.y); kk[2]=i2bf(ka0.z); kk[3]=i2bf(ka0.w);
        kk[4]=i2bf(ka1.x); kk[5]=i2bf(ka1.y); kk[6]=i2bf(ka1.z); kk[7]=i2bf(ka1.w);
        *(short8*)&k_lds[buf][(krow * NDIM + dk) ^ ((krow & 7) << 3)] = kk;
        short* vb = &vt_lds[buf][(dgv * 4) * VTS + kv2 * 2];
        short2v c0 = { i2bf(va0.x), i2bf(va1.x) };
        short2v c1 = { i2bf(va0.y), i2bf(va1.y) };
        short2v c2 = { i2bf(va0.z), i2bf(va1.z) };
        short2v c3 = { i2bf(va0.w), i2bf(va1.w) };
        *(short2v*)(vb + 0 * VTS) = c0;
        *(short2v*)(vb + 1 * VTS) = c1;
        *(short2v*)(vb + 2 * VTS) = c2;
        *(short2v*)(vb + 3 * VTS) = c3;
    };

    ISSUE(0);
    for (int tt = 0; tt < nt; ++tt) {
        WRITE(tt);
        if (tt + 1 < nt) ISSUE(tt + 1);
        __syncthreads();

        const int kv0 = tt * BKV;
        if (kv0 > q_hi) continue;        // wave-uniform causal skip
        const int buf = tt & 1;

        // ---- K fragments (A-operand: [16 kv][32 d-chunk]) ----
        short8 kb0[4], kb1[4];
        #pragma unroll
        for (int c = 0; c < 4; ++c) {
            const int d = c * 32 + g * 8;
            const int sw = (fr & 7) << 3;
            kb0[c] = *(const short8*)&k_lds[buf][(fr * NDIM + d) ^ sw];
            kb1[c] = *(const short8*)&k_lds[buf][((16 + fr) * NDIM + d) ^ sw];
        }

        // ---- swapped QK^T + in-register softmax ----
        f32x4 s0 = fzero, s1 = fzero;
        __builtin_amdgcn_s_setprio(1);
        #pragma unroll
        for (int c = 0; c < 4; ++c) {
            s0 = __builtin_amdgcn_mfma_f32_16x16x32_bf16(kb0[c], qf[c], s0, 0, 0, 0);
            s1 = __builtin_amdgcn_mfma_f32_16x16x32_bf16(kb1[c], qf[c], s1, 0, 0, 0);
        }
        __builtin_amdgcn_s_setprio(0);
        // C = S^T: col = fr = q (q0+fr), row = g*4+r = kv-within-16
        const int qr = q0 + fr;
        const int g4 = g * 4;
        float p8[8];
        if (kv0 + BKV - 1 <= q0) {       // fully unmasked (wave-uniform)
            #pragma unroll
            for (int r = 0; r < 4; ++r) {
                p8[r]     = s0[r] * sc2;
                p8[4 + r] = s1[r] * sc2;
            }
        } else {
            #pragma unroll
            for (int r = 0; r < 4; ++r) {
                p8[r]     = (kv0 + g4 + r <= qr)      ? s0[r] * sc2 : -1e30f;
                p8[4 + r] = (kv0 + 16 + g4 + r <= qr) ? s1[r] * sc2 : -1e30f;
            }
        }
        float rmax = fmaxf(fmaxf(fmaxf(p8[0], p8[1]), fmaxf(p8[2], p8[3])),
                           fmaxf(fmaxf(p8[4], p8[5]), fmaxf(p8[6], p8[7])));
        rmax = fmaxf(rmax, __shfl_xor(rmax, 16, 64));
        rmax = fmaxf(rmax, __shfl_xor(rmax, 32, 64));
        if (__any((rmax > m_run) ? 1 : 0)) {   // rescale only when max grows
            const float mn = fmaxf(m_run, rmax);
            const float sf = exp2f(m_run - mn);
            m_run = mn;
            l_run *= sf;
            #pragma unroll
            for (int dt = 0; dt < 8; ++dt) {
                #pragma unroll
                for (int r = 0; r < 4; ++r) o_acc[dt][r] *= sf;
            }
        }
        float psum = 0.f;
        #pragma unroll
        for (int j = 0; j < 8; ++j) {
            p8[j] = exp2f(p8[j] - m_run);
            psum += p8[j];
        }
        psum += __shfl_xor(psum, 16, 64);
        psum += __shfl_xor(psum, 32, 64);
        l_run += psum;
        // write P^T quads: pq[w][kvHI*128 + fr*8 + e], kv = kvHI*8 + e
        {
            short4v lo = { f2bf(p8[0]), f2bf(p8[1]), f2bf(p8[2]), f2bf(p8[3]) };
            short4v hi = { f2bf(p8[4]), f2bf(p8[5]), f2bf(p8[6]), f2bf(p8[7]) };
            short* base = &pq[w][0];
            *(short4v*)(base + (g >> 1) * 128 + fr * 8 + (g & 1) * 4) = lo;
            *(short4v*)(base + (2 + (g >> 1)) * 128 + fr * 8 + (g & 1) * 4) = hi;
        }

        // ---- swapped PV: O^T[d][q] += V^T[d][kv] * P^T[kv][q] ----
        short8 pb = *(const short8*)&pq[w][g * 128 + fr * 8];
        __builtin_amdgcn_s_setprio(1);
        #pragma unroll
        for (int dt = 0; dt < 8; ++dt) {
            short8 vb = *(const short8*)&vt_lds[buf][(dt * 16 + fr) * VTS + g * 8];
            o_acc[dt] = __builtin_amdgcn_mfma_f32_16x16x32_bf16(vb, pb, o_acc[dt], 0, 0, 0);
        }
        __builtin_amdgcn_s_setprio(0);
    }

    // ---- epilogue: O^T -> out, per-lane scalar normalize ----
    {
        const int qrow = q0 + fr;
        const float sr = vscale / l_run;
        float* op = out + (size_t)(b * NSEQ + qrow) * ROWI + h * NDIM;
        #pragma unroll
        for (int dt = 0; dt < 8; ++dt) {
            f32x4 v = o_acc[dt];
            v[0] *= sr; v[1] *= sr; v[2] *= sr; v[3] *= sr;
            *(f32x4*)(op + dt * 16 + g * 4) = v;
        }
    }
}

extern "C" void kernel_launch(void* const* d_in, const int* in_sizes, int n_in,
                              void* d_out, int out_size, void* d_ws, size_t ws_size,
                              hipStream_t stream) {
    const int* qq = (const int*)d_in[0];
    const int* kq = (const int*)d_in[1];
    const int* vq = (const int*)d_in[2];
    const float* qsc = (const float*)d_in[3];
    const float* ksc = (const float*)d_in[4];
    const float* vsc = (const float*)d_in[5];
    float* out = (float*)d_out;
    (void)d_ws; (void)ws_size; (void)in_sizes; (void)n_in; (void)out_size;

    qattn_fwd<<<dim3(512), dim3(512), 0, stream>>>(qq, kq, vq, qsc, ksc, vsc, out);
}

// Round 6
// 87.214 us; speedup vs baseline: 1.3077x; 1.3077x over previous
//
#include <hip/hip_runtime.h>
#include <hip/hip_bf16.h>

typedef __attribute__((ext_vector_type(8))) short short8;
typedef __attribute__((ext_vector_type(4))) short short4v;
typedef __attribute__((ext_vector_type(4))) float f32x4;
typedef __attribute__((ext_vector_type(16))) float f32x16;
typedef __attribute__((ext_vector_type(2))) unsigned u32x2;

namespace {
constexpr int NSEQ = 2048;
constexpr int NHEAD = 16;
constexpr int NDIM = 128;
constexpr int BKV = 32;
constexpr int VTS = 40;              // vt_lds row stride (shorts); 80B = odd*16B -> conflict-free b128 column reads
constexpr int ROWI = NHEAD * NDIM;   // 2048 ints per seq row
}

// int in [-128,127] -> bf16 bits, exact
__device__ __forceinline__ short i2bf(int v) {
    union { float f; unsigned u; } x; x.f = (float)v;
    return (short)(x.u >> 16);
}

// permlane32_swap: a' = [a_lo32 | b_lo32], b' = [a_hi32 | b_hi32]
__device__ __forceinline__ void plswap(unsigned &a, unsigned &b) {
#if __has_builtin(__builtin_amdgcn_permlane32_swap)
    u32x2 r = __builtin_amdgcn_permlane32_swap(a, b, false, false);
    a = r[0]; b = r[1];
#else
    asm volatile("v_permlane32_swap_b32 %0, %1" : "+v"(a), "+v"(b));  // a,b always distinct values here
#endif
}

__global__ __launch_bounds__(256, 2)
void qattn_fwd(const int* __restrict__ qq, const int* __restrict__ kq,
               const int* __restrict__ vq, const float* __restrict__ qsc,
               const float* __restrict__ ksc, const float* __restrict__ vsc,
               float* __restrict__ out)
{
    // 512 blocks. bh = id&31 (same bh -> same XCD since 32%8==0).
    // idx pairing: CU gets idx and idx+8 -> jq pair (15-k, k): constant work per CU.
    const int id = blockIdx.x;
    const int bh = id & 31;
    const int idx = id >> 5;                       // 0..15
    const int jq = (idx < 8) ? (15 - idx) : (idx - 8);
    const int b = bh >> 4, h = bh & 15;
    const int t = threadIdx.x;
    const int lane = t & 63;
    const int w = t >> 6;                          // wave 0..3
    const int l31 = lane & 31;
    const int h5 = lane >> 5;

    __shared__ __align__(16) short k_lds[2][BKV * NDIM];   // 16 KB, XOR-swizzled rows
    __shared__ __align__(16) short vt_lds[2][NDIM * VTS];  // 20 KB, V^T [d][kv]

    const float sc2 = qsc[h] * ksc[h] * (0.08838834764831845f * 1.4426950408889634f); // /sqrt(D)*log2e
    const float vscale = vsc[h];

    const int q0 = jq * 128 + w * 32;              // this wave's 32 q rows
    const int q_hi = q0 + 31;
    const int nt = (jq + 1) * 4;                   // kv tiles staged for this block

    const int* kB = kq + (size_t)b * NSEQ * ROWI + h * NDIM;
    const int* vB = vq + (size_t)b * NSEQ * ROWI + h * NDIM;

    // ---- Q fragments (B-operand of 32x32x16): lane owns q col = q0+l31,
    //      chunk c: k-elems e=0..7 -> d = c*16 + h5*8 + e ----
    short8 qf[8];
    {
        const int* qp = qq + (size_t)(b * NSEQ + q0 + l31) * ROWI + h * NDIM + h5 * 8;
        #pragma unroll
        for (int c = 0; c < 8; ++c) {
            int4 a0 = *(const int4*)(qp + c * 16);
            int4 a1 = *(const int4*)(qp + c * 16 + 4);
            short8 f;
            f[0]=i2bf(a0.x); f[1]=i2bf(a0.y); f[2]=i2bf(a0.z); f[3]=i2bf(a0.w);
            f[4]=i2bf(a1.x); f[5]=i2bf(a1.y); f[6]=i2bf(a1.z); f[7]=i2bf(a1.w);
            qf[c] = f;
        }
    }

    f32x16 o_acc[4];                   // O^T: o_acc[dt][r] = O[d = dt*32 + (r&3)+8*(r>>2)+4*h5][q = q0+l31]
    #pragma unroll
    for (int dt = 0; dt < 4; ++dt)
        #pragma unroll
        for (int r = 0; r < 16; ++r) o_acc[dt][r] = 0.f;
    float m_run = -1e30f, l_run = 0.f; // per-lane: lane owns one q row

    // ---- staging decomposition (256 threads) ----
    const int kr  = t >> 3;            // K: 0..31
    const int dk  = (t & 7) * 16;      // K: d0
    const int kvh = t & 7;             // V: kv rows kvh*4..+3
    const int dgv = t >> 3;            // V: d cols dgv*4..+3
    int4 ka0, ka1, ka2, ka3, va0, va1, va2, va3;

    auto ISSUE = [&](int tt) {
        const int kv = tt * BKV;
        const int* kp = kB + (kv + kr) * ROWI + dk;
        ka0 = *(const int4*)kp;       ka1 = *(const int4*)(kp + 4);
        ka2 = *(const int4*)(kp + 8); ka3 = *(const int4*)(kp + 12);
        const int* vp = vB + (kv + kvh * 4) * ROWI + dgv * 4;
        va0 = *(const int4*)vp;
        va1 = *(const int4*)(vp + ROWI);
        va2 = *(const int4*)(vp + 2 * ROWI);
        va3 = *(const int4*)(vp + 3 * ROWI);
    };
    auto WRITE = [&](int tt) {
        const int buf = tt & 1;
        short8 lo, hi;
        lo[0]=i2bf(ka0.x); lo[1]=i2bf(ka0.y); lo[2]=i2bf(ka0.z); lo[3]=i2bf(ka0.w);
        lo[4]=i2bf(ka1.x); lo[5]=i2bf(ka1.y); lo[6]=i2bf(ka1.z); lo[7]=i2bf(ka1.w);
        hi[0]=i2bf(ka2.x); hi[1]=i2bf(ka2.y); hi[2]=i2bf(ka2.z); hi[3]=i2bf(ka2.w);
        hi[4]=i2bf(ka3.x); hi[5]=i2bf(ka3.y); hi[6]=i2bf(ka3.z); hi[7]=i2bf(ka3.w);
        const int sw = (kr & 7) << 3;
        *(short8*)&k_lds[buf][(kr * NDIM + dk) ^ sw]     = lo;
        *(short8*)&k_lds[buf][(kr * NDIM + dk + 8) ^ sw] = hi;
        short4v c0 = { i2bf(va0.x), i2bf(va1.x), i2bf(va2.x), i2bf(va3.x) };
        short4v c1 = { i2bf(va0.y), i2bf(va1.y), i2bf(va2.y), i2bf(va3.y) };
        short4v c2 = { i2bf(va0.z), i2bf(va1.z), i2bf(va2.z), i2bf(va3.z) };
        short4v c3 = { i2bf(va0.w), i2bf(va1.w), i2bf(va2.w), i2bf(va3.w) };
        short* vb = &vt_lds[buf][(dgv * 4) * VTS + kvh * 4];
        *(short4v*)(vb + 0 * VTS) = c0;
        *(short4v*)(vb + 1 * VTS) = c1;
        *(short4v*)(vb + 2 * VTS) = c2;
        *(short4v*)(vb + 3 * VTS) = c3;
    };

    ISSUE(0);
    for (int tt = 0; tt < nt; ++tt) {
        WRITE(tt);
        if (tt + 1 < nt) ISSUE(tt + 1);
        __syncthreads();

        const int kv0 = tt * BKV;
        if (kv0 > q_hi) continue;      // wave-uniform causal skip
        const int buf = tt & 1;

        // ---- QK^T (swapped): C = S^T, col = l31 = q, row = (r&3)+8*(r>>2)+4*h5 = kv ----
        f32x16 s;
        #pragma unroll
        for (int r = 0; r < 16; ++r) s[r] = 0.f;
        __builtin_amdgcn_s_setprio(1);
        #pragma unroll
        for (int c = 0; c < 8; ++c) {
            const short8 kb = *(const short8*)&k_lds[buf][(l31 * NDIM + c * 16 + h5 * 8) ^ ((l31 & 7) << 3)];
            s = __builtin_amdgcn_mfma_f32_32x32x16_bf16(kb, qf[c], s, 0, 0, 0);
        }
        __builtin_amdgcn_s_setprio(0);

        // ---- mask (diag tile only) ----
        float sv[16];
        if (kv0 < q0) {                        // fully unmasked
            #pragma unroll
            for (int r = 0; r < 16; ++r) sv[r] = s[r];
        } else {                               // diag: kv0 == q0 -> mask kvr <= l31
            #pragma unroll
            for (int r = 0; r < 16; ++r) {
                const int kvr = (r & 3) + 8 * (r >> 2) + 4 * h5;
                sv[r] = (kvr <= l31) ? s[r] : -1e30f;
            }
        }

        // ---- in-register softmax (raw-s domain; sc2 > 0 so max commutes) ----
        float rmax = sv[0];
        #pragma unroll
        for (int r = 1; r < 16; ++r) rmax = fmaxf(rmax, sv[r]);
        rmax = fmaxf(rmax, __shfl_xor(rmax, 32, 64));      // cross-half max (proven primitive)
        const bool need = (rmax - m_run) * sc2 > 8.0f;     // T13 defer-rescale
        if (__any((int)need)) {
            const float mn = fmaxf(m_run, rmax);
            const float sf = exp2f((m_run - mn) * sc2);
            m_run = mn;
            l_run *= sf;
            #pragma unroll
            for (int dt = 0; dt < 4; ++dt)
                #pragma unroll
                for (int r = 0; r < 16; ++r) o_acc[dt][r] *= sf;
        }
        const float nm = m_run * sc2;
        float p[16];
        float ps = 0.f;
        #pragma unroll
        for (int r = 0; r < 16; ++r) {
            p[r] = exp2f(__builtin_fmaf(sv[r], sc2, -nm));
            ps += p[r];
        }
        ps += __shfl_xor(ps, 32, 64);                      // cross-half sum
        l_run += ps;

        // ---- P -> bf16 B-frags fully in-register (T12): cvt_pk pairs + permlane32_swap ----
        // reg r holds kv = (r&3)+8*(r>>2)+4*h5. Pair (p[2i],p[2i+1]) -> one u32 of 2 bf16.
        // plswap(A,B): A' = [A_lo | B_lo], B' = [A_hi | B_hi] -> fills both frag words.
        unsigned pw0[4], pw1[4];
        {
            unsigned A0, A1, B0, B1;
            asm("v_cvt_pk_bf16_f32 %0, %1, %2" : "=v"(A0) : "v"(p[0]),  "v"(p[1]));
            asm("v_cvt_pk_bf16_f32 %0, %1, %2" : "=v"(A1) : "v"(p[2]),  "v"(p[3]));
            asm("v_cvt_pk_bf16_f32 %0, %1, %2" : "=v"(B0) : "v"(p[4]),  "v"(p[5]));
            asm("v_cvt_pk_bf16_f32 %0, %1, %2" : "=v"(B1) : "v"(p[6]),  "v"(p[7]));
            plswap(A0, B0);
            plswap(A1, B1);
            pw0[0] = A0; pw0[1] = A1; pw0[2] = B0; pw0[3] = B1;
            asm("v_cvt_pk_bf16_f32 %0, %1, %2" : "=v"(A0) : "v"(p[8]),  "v"(p[9]));
            asm("v_cvt_pk_bf16_f32 %0, %1, %2" : "=v"(A1) : "v"(p[10]), "v"(p[11]));
            asm("v_cvt_pk_bf16_f32 %0, %1, %2" : "=v"(B0) : "v"(p[12]), "v"(p[13]));
            asm("v_cvt_pk_bf16_f32 %0, %1, %2" : "=v"(B1) : "v"(p[14]), "v"(p[15]));
            plswap(A0, B0);
            plswap(A1, B1);
            pw1[0] = A0; pw1[1] = A1; pw1[2] = B0; pw1[3] = B1;
        }
        union { unsigned u[4]; short8 v; } pf0, pf1;
        pf0.u[0]=pw0[0]; pf0.u[1]=pw0[1]; pf0.u[2]=pw0[2]; pf0.u[3]=pw0[3];
        pf1.u[0]=pw1[0]; pf1.u[1]=pw1[1]; pf1.u[2]=pw1[2]; pf1.u[3]=pw1[3];

        // ---- PV (swapped): O^T[d][q] += V^T[d][kv] * P^T[kv][q] ----
        __builtin_amdgcn_s_setprio(1);
        #pragma unroll
        for (int dt = 0; dt < 4; ++dt) {
            const int drow = dt * 32 + l31;
            const short8 vb0 = *(const short8*)&vt_lds[buf][drow * VTS + h5 * 8];
            o_acc[dt] = __builtin_amdgcn_mfma_f32_32x32x16_bf16(vb0, pf0.v, o_acc[dt], 0, 0, 0);
            const short8 vb1 = *(const short8*)&vt_lds[buf][drow * VTS + 16 + h5 * 8];
            o_acc[dt] = __builtin_amdgcn_mfma_f32_32x32x16_bf16(vb1, pf1.v, o_acc[dt], 0, 0, 0);
        }
        __builtin_amdgcn_s_setprio(0);
    }

    // ---- epilogue: O^T -> out, per-lane scalar normalize ----
    {
        const float sr = vscale / l_run;
        float* op = out + (size_t)(b * NSEQ + q0 + l31) * ROWI + h * NDIM;
        #pragma unroll
        for (int dt = 0; dt < 4; ++dt) {
            #pragma unroll
            for (int gq = 0; gq < 4; ++gq) {
                f32x4 v = { o_acc[dt][gq * 4 + 0] * sr, o_acc[dt][gq * 4 + 1] * sr,
                            o_acc[dt][gq * 4 + 2] * sr, o_acc[dt][gq * 4 + 3] * sr };
                *(f32x4*)(op + dt * 32 + 8 * gq + 4 * h5) = v;
            }
        }
    }
}

extern "C" void kernel_launch(void* const* d_in, const int* in_sizes, int n_in,
                              void* d_out, int out_size, void* d_ws, size_t ws_size,
                              hipStream_t stream) {
    const int* qq = (const int*)d_in[0];
    const int* kq = (const int*)d_in[1];
    const int* vq = (const int*)d_in[2];
    const float* qsc = (const float*)d_in[3];
    const float* ksc = (const float*)d_in[4];
    const float* vsc = (const float*)d_in[5];
    float* out = (float*)d_out;
    (void)d_ws; (void)ws_size; (void)in_sizes; (void)n_in; (void)out_size;

    qattn_fwd<<<dim3(512), dim3(256), 0, stream>>>(qq, kq, vq, qsc, ksc, vsc, out);
}